// Round 3
// baseline (532.797 us; speedup 1.0000x reference)
//
#include <hip/hip_runtime.h>

#define NUM_WORDS 31995
#define DIM 128
#define LATENT 10000
#define LPAD 10048
#define NT 157          // LPAD/64
#define TOTAL_NGRAMS 639900
#define VOCAB 32000
#define LOG2E 1.44269504f

typedef __attribute__((ext_vector_type(8))) short bf16x8;
typedef __attribute__((ext_vector_type(4))) float f32x4;
typedef __attribute__((ext_vector_type(8))) unsigned short u16x8;
typedef __attribute__((ext_vector_type(4))) short s16x4;
typedef __attribute__((ext_vector_type(2))) unsigned int u32x2;

__device__ __forceinline__ unsigned short f2b(float f){
  union { float f; unsigned int u; } a; a.f = f;
  unsigned int r = (a.u + 0x7fffu + ((a.u >> 16) & 1u)) >> 16;
  return (unsigned short)r;
}

__device__ __forceinline__ unsigned int cvtpk(float a, float b){
  unsigned int r;
  asm("v_cvt_pk_bf16_f32 %0, %1, %2" : "=v"(r) : "v"(a), "v"(b));
  return r;
}

__device__ __forceinline__ void gload16(const void* g, void* l){
  __builtin_amdgcn_global_load_lds(
      (const __attribute__((address_space(1))) unsigned int*)g,
      (__attribute__((address_space(3))) unsigned int*)l, 16, 0, 0);
}

// ---- Kernel A: segment start offsets via binary search ----
__global__ void k_starts(const int* __restrict__ seg, int* __restrict__ starts){
  int w = blockIdx.x * blockDim.x + threadIdx.x;
  if (w > NUM_WORDS) return;
  int lo = 0, hi = TOTAL_NGRAMS;
  while (lo < hi){ int mid = (lo + hi) >> 1; if (seg[mid] < w) lo = mid + 1; else hi = mid; }
  starts[w] = lo;
}

// ---- Kernel B: ragged mean-pool + tanh -> lang f32 rows + prescaled bf16 Q ----
__global__ void k_bag(const int* __restrict__ ngram_ids, const float* __restrict__ table,
                      const int* __restrict__ starts, float* __restrict__ langf,
                      unsigned short* __restrict__ langbf){
  int w = blockIdx.x; int d = threadIdx.x;
  if (w >= NUM_WORDS){ langbf[w*DIM + d] = 0; return; }
  int s = starts[w], e = starts[w+1];
  float acc = 0.f;
  for (int t = s; t < e; ++t)
    acc += table[(long)ngram_ids[t]*DIM + d];
  float val = 0.f; int c = e - s;
  if (c > 0) val = tanhf(acc / (float)c);
  langf[(long)(4+w)*DIM + d] = val;
  langbf[w*DIM + d] = f2b(val * LOG2E);   // Q prescaled: exp(S) = exp2(S')
}

// ---- Prep K: latent f32 -> bf16 row-major [LPAD][128], zero-padded ----
__global__ void k_prep_k(const float* __restrict__ latent, unsigned short* __restrict__ Kbf){
  int i = blockIdx.x*256 + threadIdx.x;
  if (i >= LPAD*DIM/8) return;
  int base = i*8;
  u16x8 v;
  if (base < LATENT*DIM){
    float4 a = *(const float4*)(latent + base);
    float4 b = *(const float4*)(latent + base + 4);
    v = (u16x8){f2b(a.x),f2b(a.y),f2b(a.z),f2b(a.w),f2b(b.x),f2b(b.y),f2b(b.z),f2b(b.w)};
  } else {
    v = (u16x8){0,0,0,0,0,0,0,0};
  }
  *(u16x8*)(Kbf + base) = v;
}

// ---- Prep V: latent -> bf16 transposed [128][LPAD] ----
__global__ void k_prep_v(const float* __restrict__ latent, unsigned short* __restrict__ VtG){
  __shared__ unsigned short TL[128*66];
  const int l0 = blockIdx.x*64;
  const int tid = threadIdx.x;
  #pragma unroll
  for (int it = 0; it < 32; ++it){
    int idx = it*256 + tid;
    int lr = idx >> 7, d = idx & 127;
    float x = (l0 + lr < LATENT) ? latent[(size_t)(l0+lr)*DIM + d] : 0.f;
    TL[d*66 + lr] = f2b(x);
  }
  __syncthreads();
  #pragma unroll
  for (int it = 0; it < 8; ++it){
    int idx4 = it*256 + tid;
    int d = idx4 >> 4, j = idx4 & 15;
    s16x4 v = (s16x4){ (short)TL[d*66 + j*4], (short)TL[d*66 + j*4 + 1],
                       (short)TL[d*66 + j*4 + 2], (short)TL[d*66 + j*4 + 3] };
    *(s16x4*)(VtG + (size_t)d*LPAD + l0 + j*4) = v;
  }
}

// ---- Kernel C: flash (no-max softmax), swapped operands, m=4, l-split 4 ----
// grid = 125 q-blocks x 4 l-parts. 4 waves x 64 q-rows. S^T = mfma(Kfrag, Qfrag):
// lane holds P^T[l][q=lm] -> cvt_pk pairs -> b64 LDS write; O^T = mfma(Vtfrag, Pfrag).
// Partials accumulated to Oacc/sbuf with f32 atomics; normalized in k_gather.
__global__ __launch_bounds__(256, 2) void k_flash(
    const unsigned short* __restrict__ langbf,
    const unsigned short* __restrict__ Kbf,
    const unsigned short* __restrict__ VtG,
    float* __restrict__ Oacc, float* __restrict__ sbuf)
{
  extern __shared__ unsigned short sm[];
  unsigned short* KL = sm;                   // 2 x [64][128], 16B-blk ^ (row&7)
  unsigned short* VL = sm + 16384;           // 2 x [128][64], 16B-blk ^ (d&7)
  const int tid = threadIdx.x;
  const int wv = tid >> 6;
  const int l  = tid & 63;
  const int lm = l & 15, lg = l >> 4;
  unsigned short* PB = sm + 32768 + wv*2048; // per-wave [64 q][32 l], blk ^ (q&3)

  const int qb = (blockIdx.x % 125) * 256 + wv*64;
  const int h  = blockIdx.x / 125;
  const int ts = h*40;
  const int te = (h==3) ? NT : ts+40;

  // Q fragments (B-operand; same per-lane data as A-layout): row/col=lm, k contiguous
  bf16x8 qf[4][4];
  #pragma unroll
  for (int m = 0; m < 4; ++m)
    #pragma unroll
    for (int ks = 0; ks < 4; ++ks)
      qf[m][ks] = *(const bf16x8*)(langbf + (size_t)(qb + m*16 + lm)*DIM + ks*32 + lg*8);

  int kofs[4], vofs[4];
  #pragma unroll
  for (int j = 0; j < 4; ++j){
    int c   = wv*4 + j;
    int row = c*4 + (l >> 4);
    kofs[j] = row*128 + (((l & 15) ^ (row & 7))*8);
    int d   = c*8 + (l >> 3);
    vofs[j] = d*LPAD + (((l & 7) ^ (d & 7))*8);
  }

  f32x4 oacc[4][8];
  #pragma unroll
  for (int m = 0; m < 4; ++m)
    #pragma unroll
    for (int nd = 0; nd < 8; ++nd) oacc[m][nd] = (f32x4){0.f,0.f,0.f,0.f};
  float s_r[4] = {0.f,0.f,0.f,0.f};

#define STAGE(T, B) do { \
    const unsigned short* kb_ = Kbf + (size_t)(T)*8192; \
    const unsigned short* vb_ = VtG + (T)*64; \
    unsigned short* kl_ = KL + (B)*8192; \
    unsigned short* vl_ = VL + (B)*8192; \
    _Pragma("unroll") \
    for (int j = 0; j < 4; ++j) gload16(kb_ + kofs[j], kl_ + (wv*4+j)*512); \
    _Pragma("unroll") \
    for (int j = 0; j < 4; ++j) gload16(vb_ + vofs[j], vl_ + (wv*4+j)*512); \
  } while(0)

  STAGE(ts, 0);
  __syncthreads();

  for (int t = ts; t < te; ++t){
    const int buf = (t - ts) & 1;
    if (t + 1 < te) STAGE(t+1, buf^1);
    const unsigned short* Kb = KL + buf*8192;
    const unsigned short* Vb = VL + buf*8192;
    const int l0 = t*64;
    const bool tail = (l0 + 64 > LATENT);

    #pragma unroll
    for (int half = 0; half < 2; ++half){
      // S^T for n = 2*half .. 2*half+1; P into PB (32-l half-buffer)
      #pragma unroll
      for (int nn = 0; nn < 2; ++nn){
        const int n = half*2 + nn;
        f32x4 ss[4];
        #pragma unroll
        for (int m = 0; m < 4; ++m) ss[m] = (f32x4){0.f,0.f,0.f,0.f};
        #pragma unroll
        for (int ks = 0; ks < 4; ++ks){
          const int row = n*16 + lm;
          bf16x8 kf = *(const bf16x8*)(Kb + row*128 + (((ks*4+lg) ^ (lm & 7))*8));
          #pragma unroll
          for (int m = 0; m < 4; ++m)
            ss[m] = __builtin_amdgcn_mfma_f32_16x16x32_bf16(kf, qf[m][ks], ss[m], 0, 0, 0);
        }
        #pragma unroll
        for (int m = 0; m < 4; ++m){
          float p[4];
          #pragma unroll
          for (int r = 0; r < 4; ++r){
            float e = exp2f(ss[m][r]);
            if (tail && (l0 + n*16 + lg*4 + r >= LATENT)) e = 0.f;
            p[r] = e;
          }
          s_r[m] += (p[0] + p[1]) + (p[2] + p[3]);
          u32x2 pk = (u32x2){cvtpk(p[0], p[1]), cvtpk(p[2], p[3])};
          const int q   = m*16 + lm;
          const int blk = (nn*2 + (lg >> 1)) ^ (q & 3);
          *(u32x2*)(PB + q*32 + blk*8 + (lg & 1)*4) = pk;   // ds_write_b64
        }
      }
      // PV for this half: O^T += Vt . P  (k-chunk of 32 l)
      bf16x8 pf[4];
      #pragma unroll
      for (int m = 0; m < 4; ++m){
        const int q = m*16 + lm;
        pf[m] = *(const bf16x8*)(PB + q*32 + ((lg ^ (q & 3))*8));
      }
      #pragma unroll
      for (int nd = 0; nd < 8; ++nd){
        const int d = nd*16 + lm;
        bf16x8 vt = *(const bf16x8*)(Vb + d*64 + (((half*4 + lg) ^ (d & 7))*8));
        #pragma unroll
        for (int m = 0; m < 4; ++m)
          oacc[m][nd] = __builtin_amdgcn_mfma_f32_16x16x32_bf16(vt, pf[m], oacc[m][nd], 0, 0, 0);
      }
    }
    __syncthreads();   // drains vmcnt for STAGE(t+1); all waves done with buf
  }

  // epilogue: reduce s across lg groups; atomically accumulate partials
  #pragma unroll
  for (int m = 0; m < 4; ++m){
    float s = s_r[m];
    s += __shfl_xor(s, 16, 64);
    s += __shfl_xor(s, 32, 64);
    const int qg = qb + m*16 + lm;
    if (lg == 0) atomicAdd(&sbuf[qg], s);
    float* orow = Oacc + (size_t)qg*DIM;
    #pragma unroll
    for (int nd = 0; nd < 8; ++nd)
      #pragma unroll
      for (int r = 0; r < 4; ++r)
        atomicAdd(&orow[nd*16 + lg*4 + r], oacc[m][nd][r]);
  }
#undef STAGE
}

// ---- Kernel D: special rows 0..3 and mask row 31999 into lang table ----
__global__ void k_special(const float* __restrict__ sp, const float* __restrict__ maskemb,
                          float* __restrict__ langf){
  int d = threadIdx.x; int r = blockIdx.x;
  if (r < 4) langf[r*DIM + d] = sp[r*DIM + d];
  else       langf[(long)(VOCAB-1)*DIM + d] = maskemb[d];
}

// ---- Kernel E: out = lang[x] (+ Oacc[x-4]/s for word tokens) ----
__global__ void k_gather(const int* __restrict__ x, const float* __restrict__ langf,
                         const float* __restrict__ Oacc, const float* __restrict__ sbuf,
                         float* __restrict__ out){
  int i = blockIdx.x*256 + threadIdx.x;     // float4 index
  int tok = x[i >> 5];
  int d4  = i & 31;
  float4 v = ((const float4*)langf)[(long)tok*32 + d4];
  if (tok >= 4 && tok < VOCAB-1){
    int w = tok - 4;
    float s = sbuf[w];
    float4 o = ((const float4*)Oacc)[(long)w*32 + d4];
    v.x += o.x / s; v.y += o.y / s; v.z += o.z / s; v.w += o.w / s;
  }
  ((float4*)out)[i] = v;
}

extern "C" void kernel_launch(void* const* d_in, const int* in_sizes, int n_in,
                              void* d_out, int out_size, void* d_ws, size_t ws_size,
                              hipStream_t stream){
  const int*   x         = (const int*)d_in[0];
  const int*   ngram_ids = (const int*)d_in[1];
  const int*   seg       = (const int*)d_in[2];
  const float* table     = (const float*)d_in[3];
  const float* latent    = (const float*)d_in[4];
  const float* special   = (const float*)d_in[5];
  const float* maskemb   = (const float*)d_in[6];
  float* out = (float*)d_out;

  char* ws = (char*)d_ws;
  int* starts            = (int*)ws;                           // 131,072 B
  unsigned short* langbf = (unsigned short*)(ws + 131072);     // 8,192,000 B
  float* langf           = (float*)(ws + 8323072);             // 16,384,000 B
  unsigned short* Kbf    = (unsigned short*)(ws + 24707072);   // 2,572,288 B
  unsigned short* VtG    = (unsigned short*)(ws + 27279360);   // 2,572,288 B
  float* Oacc            = (float*)(ws + 29851648);            // 16,384,000 B
  float* sbuf            = (float*)(ws + 46235648);            // 128,000 B

  const int SMEM = 2*64*128*2 + 2*128*64*2 + 4*64*32*2;        // 81,920 B
  (void)hipFuncSetAttribute(reinterpret_cast<const void*>(k_flash),
                            hipFuncAttributeMaxDynamicSharedMemorySize, SMEM);

  hipMemsetAsync(Oacc, 0, 16384000, stream);
  hipMemsetAsync(sbuf, 0, 128000, stream);

  k_starts <<<(NUM_WORDS + 1 + 255)/256, 256, 0, stream>>>(seg, starts);
  k_prep_k <<<(LPAD*DIM/8 + 255)/256, 256, 0, stream>>>(latent, Kbf);
  k_prep_v <<<NT, 256, 0, stream>>>(latent, VtG);
  k_bag    <<<VOCAB, DIM, 0, stream>>>(ngram_ids, table, starts, langf, langbf);
  k_special<<<5, DIM, 0, stream>>>(special, maskemb, langf);
  k_flash  <<<500, 256, SMEM, stream>>>(langbf, Kbf, VtG, Oacc, sbuf);
  k_gather <<<(8*512*DIM/4)/256, 256, 0, stream>>>(x, langf, Oacc, sbuf, out);
}

// Round 4
// 122.542 us; speedup vs baseline: 4.3479x; 4.3479x over previous
//
#include <hip/hip_runtime.h>

#define NUM_WORDS 31995
#define DIM 128
#define LATENT 10000
#define LPAD 10048
#define NT 157          // LPAD/64
#define NH 32           // l-split parts
#define TOTAL_NGRAMS 639900
#define VOCAB 32000
#define LOG2E 1.44269504f
#define CPAD 4224       // compact capacity: 4096 words + 5 special rows + pad

typedef __attribute__((ext_vector_type(8))) short bf16x8;
typedef __attribute__((ext_vector_type(4))) float f32x4;
typedef __attribute__((ext_vector_type(8))) unsigned short u16x8;
typedef __attribute__((ext_vector_type(4))) short s16x4;
typedef __attribute__((ext_vector_type(2))) unsigned int u32x2;

__device__ __forceinline__ unsigned short f2b(float f){
  union { float f; unsigned int u; } a; a.f = f;
  unsigned int r = (a.u + 0x7fffu + ((a.u >> 16) & 1u)) >> 16;
  return (unsigned short)r;
}
__device__ __forceinline__ float b2f(unsigned int lo16){
  union { unsigned int u; float f; } a; a.u = lo16 << 16; return a.f;
}
__device__ __forceinline__ unsigned int cvtpk(float a, float b){
  unsigned int r;
  asm("v_cvt_pk_bf16_f32 %0, %1, %2" : "=v"(r) : "v"(a), "v"(b));
  return r;
}
__device__ __forceinline__ void gload16(const void* g, void* l){
  __builtin_amdgcn_global_load_lds(
      (const __attribute__((address_space(1))) unsigned int*)g,
      (__attribute__((address_space(3))) unsigned int*)l, 16, 0, 0);
}

// ---- segment starts via binary search (segment_ids sorted) ----
__global__ void k_starts(const int* __restrict__ seg, int* __restrict__ starts){
  int w = blockIdx.x * blockDim.x + threadIdx.x;
  if (w > NUM_WORDS) return;
  int lo = 0, hi = TOTAL_NGRAMS;
  while (lo < hi){ int mid = (lo + hi) >> 1; if (seg[mid] < w) lo = mid + 1; else hi = mid; }
  starts[w] = lo;
}

// ---- mark used word tokens ----
__global__ void k_mark(const int* __restrict__ x, int* __restrict__ flags){
  int i = blockIdx.x*256 + threadIdx.x;
  if (i >= 4096) return;
  int tok = x[i];
  if (tok >= 4 && tok < VOCAB-1) flags[tok - 4] = 1;
}

// ---- compact used words into list/inv ----
__global__ void k_compact(const int* __restrict__ flags, int* __restrict__ list,
                          int* __restrict__ inv, int* __restrict__ count){
  int w = blockIdx.x*256 + threadIdx.x;
  if (w >= NUM_WORDS) return;
  if (flags[w]){
    int ci = atomicAdd(count, 1);
    list[ci] = w;
    inv[w] = ci;
  }
}

// ---- ragged mean-pool + tanh for USED words only (compact rows) ----
__global__ void k_bag(const int* __restrict__ ngram_ids, const float* __restrict__ table,
                      const int* __restrict__ starts, const int* __restrict__ list,
                      const int* __restrict__ count,
                      float* __restrict__ langfc, unsigned short* __restrict__ langbf){
  int ci = blockIdx.x;
  if (ci >= count[0]) return;
  int w = list[ci];
  int d = threadIdx.x;
  int s = starts[w], e = starts[w+1];
  float acc = 0.f;
  for (int t = s; t < e; ++t)
    acc += table[(size_t)ngram_ids[t]*DIM + d];
  float val = (e > s) ? tanhf(acc / (float)(e - s)) : 0.f;
  langfc[(size_t)ci*DIM + d] = val;
  langbf[ci*DIM + d] = f2b(val * LOG2E);   // Q prescaled: exp(S) = exp2(S')
}

// ---- latent f32 -> bf16 row-major [LPAD][128], zero-padded ----
__global__ void k_prep_k(const float* __restrict__ latent, unsigned short* __restrict__ Kbf){
  int i = blockIdx.x*256 + threadIdx.x;
  if (i >= LPAD*DIM/8) return;
  int base = i*8;
  u16x8 v;
  if (base < LATENT*DIM){
    float4 a = *(const float4*)(latent + base);
    float4 b = *(const float4*)(latent + base + 4);
    v = (u16x8){f2b(a.x),f2b(a.y),f2b(a.z),f2b(a.w),f2b(b.x),f2b(b.y),f2b(b.z),f2b(b.w)};
  } else {
    v = (u16x8){0,0,0,0,0,0,0,0};
  }
  *(u16x8*)(Kbf + base) = v;
}

// ---- latent -> bf16 transposed [128][LPAD] ----
__global__ void k_prep_v(const float* __restrict__ latent, unsigned short* __restrict__ VtG){
  __shared__ unsigned short TL[128*66];
  const int l0 = blockIdx.x*64;
  const int tid = threadIdx.x;
  #pragma unroll
  for (int it = 0; it < 32; ++it){
    int idx = it*256 + tid;
    int lr = idx >> 7, d = idx & 127;
    float x = (l0 + lr < LATENT) ? latent[(size_t)(l0+lr)*DIM + d] : 0.f;
    TL[d*66 + lr] = f2b(x);
  }
  __syncthreads();
  #pragma unroll
  for (int it = 0; it < 8; ++it){
    int idx4 = it*256 + tid;
    int d = idx4 >> 4, j = idx4 & 15;
    s16x4 v = (s16x4){ (short)TL[d*66 + j*4], (short)TL[d*66 + j*4 + 1],
                       (short)TL[d*66 + j*4 + 2], (short)TL[d*66 + j*4 + 3] };
    *(s16x4*)(VtG + (size_t)d*LPAD + l0 + j*4) = v;
  }
}

// ---- special rows 0..3 -> langfc[4096..4099]; mask -> langfc[4100] ----
__global__ void k_special(const float* __restrict__ sp, const float* __restrict__ maskemb,
                          float* __restrict__ langfc){
  int d = threadIdx.x; int r = blockIdx.x;
  if (r < 4) langfc[(size_t)(4096+r)*DIM + d] = sp[r*DIM + d];
  else       langfc[(size_t)4100*DIM + d] = maskemb[d];
}

// ---- flash attention on compact rows, 32-way l-split, bf16 partial outputs ----
// 4 waves x 64 q (m=4). S^T = mfma(Kfrag, Qfrag). PB chunk-rotated (pc=(c+q/4)&3):
// P-read 2-way (free). Tile body reordered: QK1 between P-write0 and P-read0.
__global__ __launch_bounds__(256, 2) void k_flash(
    const unsigned short* __restrict__ langbf,
    const unsigned short* __restrict__ Kbf,
    const unsigned short* __restrict__ VtG,
    unsigned short* __restrict__ Opart, float* __restrict__ sbuf)
{
  extern __shared__ unsigned short sm[];
  unsigned short* KL = sm;                   // 2 x [64][128], 16B-blk ^ (row&7)
  unsigned short* VL = sm + 16384;           // 2 x [128][64], 16B-blk ^ (d&7)
  const int tid = threadIdx.x;
  const int wv = tid >> 6;
  const int l  = tid & 63;
  const int lm = l & 15, lg = l >> 4;
  unsigned short* PB = sm + 32768 + wv*2048; // per-wave [64 q][4 chunks], rotated

  const int h    = blockIdx.x >> 4;          // 0..31
  const int qblk = blockIdx.x & 15;          // 0..15
  const int qb   = qblk*256 + wv*64;
  const int ts = (h*NT)/NH;
  const int te = ((h+1)*NT)/NH;

  // Q fragments (B-operand): col=lm, k = lg*8 + i
  bf16x8 qf[4][4];
  #pragma unroll
  for (int m = 0; m < 4; ++m)
    #pragma unroll
    for (int ks = 0; ks < 4; ++ks)
      qf[m][ks] = *(const bf16x8*)(langbf + (size_t)(qb + m*16 + lm)*DIM + ks*32 + lg*8);

  int kofs[4], vofs[4];
  #pragma unroll
  for (int j = 0; j < 4; ++j){
    int c   = wv*4 + j;
    int row = c*4 + (l >> 4);
    kofs[j] = row*128 + (((l & 15) ^ (row & 7))*8);
    int d   = c*8 + (l >> 3);
    vofs[j] = d*LPAD + (((l & 7) ^ (d & 7))*8);
  }

  f32x4 oacc[4][8];
  #pragma unroll
  for (int m = 0; m < 4; ++m)
    #pragma unroll
    for (int nd = 0; nd < 8; ++nd) oacc[m][nd] = (f32x4){0.f,0.f,0.f,0.f};
  float s_r[4] = {0.f,0.f,0.f,0.f};

#define STAGE(T, B) do { \
    const unsigned short* kb_ = Kbf + (size_t)(T)*8192; \
    const unsigned short* vb_ = VtG + (T)*64; \
    unsigned short* kl_ = KL + (B)*8192; \
    unsigned short* vl_ = VL + (B)*8192; \
    _Pragma("unroll") \
    for (int j = 0; j < 4; ++j) gload16(kb_ + kofs[j], kl_ + (wv*4+j)*512); \
    _Pragma("unroll") \
    for (int j = 0; j < 4; ++j) gload16(vb_ + vofs[j], vl_ + (wv*4+j)*512); \
  } while(0)

// QK for half HH into SS[2][4]
#define QK_HALF(HH, SS) do { \
    _Pragma("unroll") \
    for (int nn = 0; nn < 2; ++nn){ \
      const int n = (HH)*2 + nn; \
      _Pragma("unroll") \
      for (int m = 0; m < 4; ++m) SS[nn][m] = (f32x4){0.f,0.f,0.f,0.f}; \
      __builtin_amdgcn_s_setprio(1); \
      _Pragma("unroll") \
      for (int ks = 0; ks < 4; ++ks){ \
        bf16x8 kf = *(const bf16x8*)(Kb + (n*16+lm)*128 + (((ks*4+lg) ^ (lm & 7))*8)); \
        _Pragma("unroll") \
        for (int m = 0; m < 4; ++m) \
          SS[nn][m] = __builtin_amdgcn_mfma_f32_16x16x32_bf16(kf, qf[m][ks], SS[nn][m], 0, 0, 0); \
      } \
      __builtin_amdgcn_s_setprio(0); \
    } \
  } while(0)

// exp + pack + rotated P-write for half HH from SS
#define PACK_HALF(HH, SS) do { \
    _Pragma("unroll") \
    for (int nn = 0; nn < 2; ++nn){ \
      const int n = (HH)*2 + nn; \
      _Pragma("unroll") \
      for (int m = 0; m < 4; ++m){ \
        float p[4]; \
        _Pragma("unroll") \
        for (int r = 0; r < 4; ++r){ \
          float e = exp2f(SS[nn][m][r]); \
          if (tail && (l0 + n*16 + lg*4 + r >= LATENT)) e = 0.f; \
          p[r] = e; \
        } \
        s_r[m] += (p[0] + p[1]) + (p[2] + p[3]); \
        u32x2 pk = (u32x2){cvtpk(p[0], p[1]), cvtpk(p[2], p[3])}; \
        const int q  = m*16 + lm; \
        const int c  = nn*2 + (lg >> 1); \
        const int pc = (c + (lm >> 2)) & 3; \
        *(u32x2*)(PB + q*32 + pc*8 + (lg & 1)*4) = pk; \
      } \
    } \
  } while(0)

// P-read + PV for half HH
#define PV_HALF(HH) do { \
    bf16x8 pf[4]; \
    _Pragma("unroll") \
    for (int m = 0; m < 4; ++m){ \
      const int q  = m*16 + lm; \
      const int pc = (lg + (lm >> 2)) & 3; \
      pf[m] = *(const bf16x8*)(PB + q*32 + pc*8); \
    } \
    __builtin_amdgcn_s_setprio(1); \
    _Pragma("unroll") \
    for (int nd = 0; nd < 8; ++nd){ \
      const int d = nd*16 + lm; \
      bf16x8 vt = *(const bf16x8*)(Vb + d*64 + ((((HH)*4 + lg) ^ (d & 7))*8)); \
      _Pragma("unroll") \
      for (int m = 0; m < 4; ++m) \
        oacc[m][nd] = __builtin_amdgcn_mfma_f32_16x16x32_bf16(vt, pf[m], oacc[m][nd], 0, 0, 0); \
    } \
    __builtin_amdgcn_s_setprio(0); \
  } while(0)

  STAGE(ts, 0);
  __syncthreads();

  for (int t = ts; t < te; ++t){
    const int buf = (t - ts) & 1;
    if (t + 1 < te) STAGE(t+1, buf^1);
    const unsigned short* Kb = KL + buf*8192;
    const unsigned short* Vb = VL + buf*8192;
    const int l0 = t*64;
    const bool tail = (l0 + 64 > LATENT);

    f32x4 sA[2][4], sB[2][4];
    QK_HALF(0, sA);
    PACK_HALF(0, sA);     // P0 write
    QK_HALF(1, sB);       // independent: hides P0 LDS round-trip
    PV_HALF(0);           // P0 read + PV
    PACK_HALF(1, sB);     // P1 write
    PV_HALF(1);           // P1 read + PV
    __syncthreads();      // drains vmcnt (stage t+1 landed) + buf reuse
  }

  // epilogue: reduce s over lg groups; bf16 partial stores (no atomics)
  #pragma unroll
  for (int m = 0; m < 4; ++m){
    float s = s_r[m];
    s += __shfl_xor(s, 16, 64);
    s += __shfl_xor(s, 32, 64);
    const int qg = qb + m*16 + lm;
    if (lg == 0) sbuf[h*CPAD + qg] = s;
    unsigned short* orow = Opart + ((size_t)h*CPAD + qg)*DIM;
    #pragma unroll
    for (int nd = 0; nd < 8; ++nd){
      u32x2 pk = (u32x2){cvtpk(oacc[m][nd][0], oacc[m][nd][1]),
                         cvtpk(oacc[m][nd][2], oacc[m][nd][3])};
      *(u32x2*)(orow + nd*16 + lg*4) = pk;
    }
  }
#undef STAGE
#undef QK_HALF
#undef PACK_HALF
#undef PV_HALF
}

// ---- gather + 32-way partial reduce ----
__global__ void k_gather(const int* __restrict__ x, const float* __restrict__ langfc,
                         const int* __restrict__ inv, const float* __restrict__ sbuf,
                         const unsigned short* __restrict__ Opart, float* __restrict__ out){
  int i = blockIdx.x*256 + threadIdx.x;     // float4 index, 131072 total
  int tok = x[i >> 5];
  int d4  = i & 31;
  bool word = (tok >= 4) && (tok < VOCAB-1);
  int ci;
  if (tok < 4) ci = 4096 + tok;
  else if (tok == VOCAB-1) ci = 4100;
  else ci = inv[tok - 4];
  float4 v = ((const float4*)langfc)[(size_t)ci*32 + d4];
  if (word){
    float s = 0.f;
    float4 o = {0.f, 0.f, 0.f, 0.f};
    for (int h = 0; h < NH; ++h){
      s += sbuf[h*CPAD + ci];
      uint2 u = *(const uint2*)(Opart + ((size_t)h*CPAD + ci)*DIM + d4*4);
      o.x += b2f(u.x & 0xffffu); o.y += b2f(u.x >> 16);
      o.z += b2f(u.y & 0xffffu); o.w += b2f(u.y >> 16);
    }
    float is = 1.f / s;
    v.x += o.x*is; v.y += o.y*is; v.z += o.z*is; v.w += o.w*is;
  }
  ((float4*)out)[i] = v;
}

extern "C" void kernel_launch(void* const* d_in, const int* in_sizes, int n_in,
                              void* d_out, int out_size, void* d_ws, size_t ws_size,
                              hipStream_t stream){
  const int*   x         = (const int*)d_in[0];
  const int*   ngram_ids = (const int*)d_in[1];
  const int*   seg       = (const int*)d_in[2];
  const float* table     = (const float*)d_in[3];
  const float* latent    = (const float*)d_in[4];
  const float* special   = (const float*)d_in[5];
  const float* maskemb   = (const float*)d_in[6];
  float* out = (float*)d_out;

  char* ws = (char*)d_ws;
  int* starts            = (int*)(ws + 0);             // 131,072
  int* flags             = (int*)(ws + 0x020000);      // 131,072
  int* inv               = (int*)(ws + 0x040000);      // 131,072
  int* list              = (int*)(ws + 0x060000);      // 16,896 (pad)
  int* count             = (int*)(ws + 0x068000);      // 256
  unsigned short* langbf = (unsigned short*)(ws + 0x070000);   // 4224*128*2 = 1,081,344
  float* langfc          = (float*)(ws + 0x180000);            // 4224*128*4 = 2,162,688
  unsigned short* Kbf    = (unsigned short*)(ws + 0x3A0000);   // 2,572,288
  unsigned short* VtG    = (unsigned short*)(ws + 0x620000);   // 2,572,288
  float* sbuf            = (float*)(ws + 0x898000);            // 32*4224*4 = 540,672
  unsigned short* Opart  = (unsigned short*)(ws + 0x920000);   // 32*4224*128*2 = 34,603,008
  // total ~44.2 MB

  const int SMEM = 2*64*128*2 + 2*128*64*2 + 4*64*32*2;        // 81,920 B
  (void)hipFuncSetAttribute(reinterpret_cast<const void*>(k_flash),
                            hipFuncAttributeMaxDynamicSharedMemorySize, SMEM);

  hipMemsetAsync(flags, 0, 131072, stream);
  hipMemsetAsync(count, 0, 256, stream);

  k_starts <<<126, 256, 0, stream>>>(seg, starts);
  k_mark   <<<16, 256, 0, stream>>>(x, flags);
  k_compact<<<125, 256, 0, stream>>>(flags, list, inv, count);
  k_prep_k <<<(LPAD*DIM/8 + 255)/256, 256, 0, stream>>>(latent, Kbf);
  k_prep_v <<<NT, 256, 0, stream>>>(latent, VtG);
  k_bag    <<<4096, DIM, 0, stream>>>(ngram_ids, table, starts, list, count, langfc, langbf);
  k_special<<<5, DIM, 0, stream>>>(special, maskemb, langfc);
  k_flash  <<<512, 256, SMEM, stream>>>(langbf, Kbf, VtG, Opart, sbuf);
  k_gather <<<512, 256, 0, stream>>>(x, langfc, inv, sbuf, Opart, out);
}

// Round 5
// 102.019 us; speedup vs baseline: 5.2225x; 1.2012x over previous
//
#include <hip/hip_runtime.h>

#define NUM_WORDS 31995
#define DIM 128
#define LATENT 10000
#define LPAD 10048
#define NT 157          // LPAD/64
#define NH 8            // l-split parts == XCD count
#define TOTAL_NGRAMS 639900
#define VOCAB 32000
#define LOG2E 1.44269504f
#define NQ 4096         // attention q rows (words only; specials need no attention)

typedef __attribute__((ext_vector_type(8))) short bf16x8;
typedef __attribute__((ext_vector_type(4))) float f32x4;
typedef __attribute__((ext_vector_type(8))) unsigned short u16x8;
typedef __attribute__((ext_vector_type(4))) short s16x4;
typedef __attribute__((ext_vector_type(2))) unsigned int u32x2;
typedef __attribute__((ext_vector_type(4))) unsigned int u32x4;

__device__ __forceinline__ unsigned short f2b(float f){
  union { float f; unsigned int u; } a; a.f = f;
  unsigned int r = (a.u + 0x7fffu + ((a.u >> 16) & 1u)) >> 16;
  return (unsigned short)r;
}
__device__ __forceinline__ float b2f(unsigned int lo16){
  union { unsigned int u; float f; } a; a.u = lo16 << 16; return a.f;
}
__device__ __forceinline__ unsigned int cvtpk(float a, float b){
  unsigned int r;
  asm("v_cvt_pk_bf16_f32 %0, %1, %2" : "=v"(r) : "v"(a), "v"(b));
  return r;
}
__device__ __forceinline__ void gload16(const void* g, void* l){
  __builtin_amdgcn_global_load_lds(
      (const __attribute__((address_space(1))) unsigned int*)g,
      (__attribute__((address_space(3))) unsigned int*)l, 16, 0, 0);
}

// ---- segment starts (binary search) + mark used word tokens ----
__global__ void k_startsmark(const int* __restrict__ seg, int* __restrict__ starts,
                             const int* __restrict__ x, int* __restrict__ flags){
  int w = blockIdx.x * blockDim.x + threadIdx.x;
  if (w < 4096){
    int tok = x[w];
    if (tok >= 4 && tok < VOCAB-1) flags[tok - 4] = 1;
  }
  if (w > NUM_WORDS) return;
  int lo = 0, hi = TOTAL_NGRAMS;
  while (lo < hi){ int mid = (lo + hi) >> 1; if (seg[mid] < w) lo = mid + 1; else hi = mid; }
  starts[w] = lo;
}

// ---- compact used words ----
__global__ void k_compact(const int* __restrict__ flags, int* __restrict__ list,
                          int* __restrict__ inv, int* __restrict__ count){
  int w = blockIdx.x*256 + threadIdx.x;
  if (w >= NUM_WORDS) return;
  if (flags[w]){
    int ci = atomicAdd(count, 1);
    list[ci] = w;
    inv[w] = ci;
  }
}

// ---- latent -> bf16 K [LPAD][128] (blocks >= NT) and V^T [128][LPAD] (blocks < NT) ----
__global__ void k_prep(const float* __restrict__ latent, unsigned short* __restrict__ Kbf,
                       unsigned short* __restrict__ VtG){
  const int tid = threadIdx.x;
  if (blockIdx.x >= NT){
    int i = (blockIdx.x - NT)*256 + tid;        // one thread per 8 elems
    int base = i*8;
    u16x8 v;
    if (base < LATENT*DIM){
      float4 a = *(const float4*)(latent + base);
      float4 b = *(const float4*)(latent + base + 4);
      v = (u16x8){f2b(a.x),f2b(a.y),f2b(a.z),f2b(a.w),f2b(b.x),f2b(b.y),f2b(b.z),f2b(b.w)};
    } else {
      v = (u16x8){0,0,0,0,0,0,0,0};
    }
    *(u16x8*)(Kbf + base) = v;
    return;
  }
  __shared__ unsigned short TL[128*66];
  const int l0 = blockIdx.x*64;
  #pragma unroll
  for (int it = 0; it < 32; ++it){
    int idx = it*256 + tid;
    int lr = idx >> 7, d = idx & 127;
    float xv = (l0 + lr < LATENT) ? latent[(size_t)(l0+lr)*DIM + d] : 0.f;
    TL[d*66 + lr] = f2b(xv);
  }
  __syncthreads();
  #pragma unroll
  for (int it = 0; it < 8; ++it){
    int idx4 = it*256 + tid;
    int d = idx4 >> 4, j = idx4 & 15;
    s16x4 v = (s16x4){ (short)TL[d*66 + j*4], (short)TL[d*66 + j*4 + 1],
                       (short)TL[d*66 + j*4 + 2], (short)TL[d*66 + j*4 + 3] };
    *(s16x4*)(VtG + (size_t)d*LPAD + l0 + j*4) = v;
  }
}

// ---- bag mean-pool + tanh (compact rows); specials in blocks 4096..4100 ----
__global__ void k_bag(const int* __restrict__ ngram_ids, const float* __restrict__ table,
                      const int* __restrict__ starts, const int* __restrict__ list,
                      const int* __restrict__ count, const float* __restrict__ sp,
                      const float* __restrict__ maskemb,
                      float* __restrict__ langfc, unsigned short* __restrict__ langbf){
  int ci = blockIdx.x;
  int d = threadIdx.x;
  if (ci >= NQ){
    int r = ci - NQ;
    langfc[(size_t)ci*DIM + d] = (r < 4) ? sp[r*DIM + d] : maskemb[d];
    return;
  }
  if (ci >= count[0]){ langbf[ci*DIM + d] = 0; return; }   // keep Q finite
  int w = list[ci];
  int s = starts[w], e = starts[w+1];
  float acc = 0.f;
  for (int t = s; t < e; ++t)
    acc += table[(size_t)ngram_ids[t]*DIM + d];
  float val = (e > s) ? tanhf(acc / (float)(e - s)) : 0.f;
  langfc[(size_t)ci*DIM + d] = val;
  langbf[ci*DIM + d] = f2b(val * LOG2E);   // Q prescaled: exp(S) = exp2(S')
}

// ---- flash attention: 2 waves x 64 shared q, each wave owns 32 l of each 64-l tile ----
// h = blockIdx & 7 -> XCD-pinned l-slice. Coalesced bf16 partial output via LDS reduce.
__global__ __launch_bounds__(128, 1) void k_flash(
    const unsigned short* __restrict__ langbf,
    const unsigned short* __restrict__ Kbf,
    const unsigned short* __restrict__ VtG,
    unsigned short* __restrict__ Opart, float* __restrict__ sbuf)
{
  extern __shared__ unsigned short sm[];
  unsigned short* KL = sm;                   // 2 x [64][128], 16B-blk ^ (row&7)
  unsigned short* VL = sm + 16384;           // 2 x [128][64], 16B-blk ^ (d&7)
  const int tid = threadIdx.x;
  const int wv = tid >> 6;
  const int l  = tid & 63;
  const int lm = l & 15, lg = l >> 4;
  unsigned short* PB = sm + 32768 + wv*2048; // per-wave P [64 q][32 l] chunk-rotated

  const int h  = blockIdx.x & 7;             // XCD-pinned l-part
  const int qb = (blockIdx.x >> 3) * 64;
  const int ts = (h*NT)/NH;
  const int te = ((h+1)*NT)/NH;

  // Q fragments (B-operand): col=lm, k = lg*8 + i  (all 64 q per wave)
  bf16x8 qf[4][4];
  #pragma unroll
  for (int m = 0; m < 4; ++m)
    #pragma unroll
    for (int ks = 0; ks < 4; ++ks)
      qf[m][ks] = *(const bf16x8*)(langbf + (size_t)(qb + m*16 + lm)*DIM + ks*32 + lg*8);

  int kofs[8], vofs[8];
  #pragma unroll
  for (int j = 0; j < 8; ++j){
    int c   = wv*8 + j;
    int row = c*4 + (l >> 4);
    kofs[j] = row*128 + (((l & 15) ^ (row & 7))*8);
    int d   = c*8 + (l >> 3);
    vofs[j] = d*LPAD + (((l & 7) ^ (d & 7))*8);
  }

  f32x4 oacc[4][8];
  #pragma unroll
  for (int m = 0; m < 4; ++m)
    #pragma unroll
    for (int nd = 0; nd < 8; ++nd) oacc[m][nd] = (f32x4){0.f,0.f,0.f,0.f};
  float s_r[4] = {0.f,0.f,0.f,0.f};

#define STAGE(T, B) do { \
    const unsigned short* kb_ = Kbf + (size_t)(T)*8192; \
    const unsigned short* vb_ = VtG + (T)*64; \
    unsigned short* kl_ = KL + (B)*8192; \
    unsigned short* vl_ = VL + (B)*8192; \
    _Pragma("unroll") \
    for (int j = 0; j < 8; ++j) gload16(kb_ + kofs[j], kl_ + (wv*8+j)*512); \
    _Pragma("unroll") \
    for (int j = 0; j < 8; ++j) gload16(vb_ + vofs[j], vl_ + (wv*8+j)*512); \
  } while(0)

#define QK_NN(NN, SS) do { \
    const int row0 = (wv*2 + (NN))*16 + lm; \
    _Pragma("unroll") \
    for (int m = 0; m < 4; ++m) SS[m] = (f32x4){0.f,0.f,0.f,0.f}; \
    __builtin_amdgcn_s_setprio(1); \
    _Pragma("unroll") \
    for (int ks = 0; ks < 4; ++ks){ \
      bf16x8 kf = *(const bf16x8*)(Kb + row0*128 + (((ks*4+lg) ^ (lm & 7))*8)); \
      _Pragma("unroll") \
      for (int m = 0; m < 4; ++m) \
        SS[m] = __builtin_amdgcn_mfma_f32_16x16x32_bf16(kf, qf[m][ks], SS[m], 0, 0, 0); \
    } \
    __builtin_amdgcn_s_setprio(0); \
  } while(0)

#define PACK_NN(NN, SS) do { \
    _Pragma("unroll") \
    for (int m = 0; m < 4; ++m){ \
      float p[4]; \
      _Pragma("unroll") \
      for (int r = 0; r < 4; ++r){ \
        float e = exp2f(SS[m][r]); \
        if (tail && (l0 + (wv*2+(NN))*16 + lg*4 + r >= LATENT)) e = 0.f; \
        p[r] = e; \
      } \
      s_r[m] += (p[0] + p[1]) + (p[2] + p[3]); \
      u32x2 pk = (u32x2){cvtpk(p[0], p[1]), cvtpk(p[2], p[3])}; \
      const int q  = m*16 + lm; \
      const int c  = (NN)*2 + (lg >> 1); \
      const int pc = (c + (lm >> 2)) & 3; \
      *(u32x2*)(PB + q*32 + pc*8 + (lg & 1)*4) = pk; \
    } \
  } while(0)

  STAGE(ts, 0);
  __syncthreads();

  for (int t = ts; t < te; ++t){
    const int buf = (t - ts) & 1;
    if (t + 1 < te) STAGE(t+1, buf^1);
    const unsigned short* Kb = KL + buf*8192;
    const unsigned short* Vb = VL + buf*8192;
    const int l0 = t*64;
    const bool tail = (l0 + 64 > LATENT);

    f32x4 sA[4], sB[4];
    QK_NN(0, sA);
    PACK_NN(0, sA);      // P chunk 0 write
    QK_NN(1, sB);        // independent MFMAs hide P0 LDS round-trip
    PACK_NN(1, sB);

    bf16x8 pf[4];
    #pragma unroll
    for (int m = 0; m < 4; ++m){
      const int q  = m*16 + lm;
      const int pc = (lg + (lm >> 2)) & 3;
      pf[m] = *(const bf16x8*)(PB + q*32 + pc*8);
    }
    __builtin_amdgcn_s_setprio(1);
    #pragma unroll
    for (int nd = 0; nd < 8; ++nd){
      const int d = nd*16 + lm;
      bf16x8 vt = *(const bf16x8*)(Vb + d*64 + (((wv*4 + lg) ^ (d & 7))*8));
      #pragma unroll
      for (int m = 0; m < 4; ++m)
        oacc[m][nd] = __builtin_amdgcn_mfma_f32_16x16x32_bf16(vt, pf[m], oacc[m][nd], 0, 0, 0);
    }
    __builtin_amdgcn_s_setprio(0);
    __syncthreads();     // drains vmcnt (stage t+1 landed) + buf reuse
  }

  // ---- epilogue: cross-wave reduce via LDS, coalesced bf16 store ----
  // per-wave O tile -> OL[wv] (16 KB each, reuse KL region), XOR-swizzled rows
  char* OLw = (char*)sm + wv*16384;
  float* SB = (float*)((char*)sm + 65536);   // [2][64] row sums (PB region)
  #pragma unroll
  for (int m = 0; m < 4; ++m){
    float s = s_r[m];
    s += __shfl_xor(s, 16, 64);
    s += __shfl_xor(s, 32, 64);
    const int q = m*16 + lm;
    if (lg == 0) SB[wv*64 + q] = s;
    #pragma unroll
    for (int nd = 0; nd < 8; ++nd){
      u32x2 pk = (u32x2){cvtpk(oacc[m][nd][0], oacc[m][nd][1]),
                         cvtpk(oacc[m][nd][2], oacc[m][nd][3])};
      int byte = q*256 + (nd*16 + lg*4)*2;
      byte ^= (q & 7) << 4;
      *(u32x2*)(OLw + byte) = pk;
    }
  }
  __syncthreads();
  // cooperative combined store: 16 KB contiguous, dwordx4
  unsigned short* orow = Opart + ((size_t)h*NQ + qb)*DIM;
  const char* OL0 = (const char*)sm;
  const char* OL1 = (const char*)sm + 16384;
  #pragma unroll
  for (int it = 0; it < 8; ++it){
    int c = it*128 + tid;                    // 16-B chunk id (1024 total)
    int sw = ((c >> 4) & 7) << 4;
    u32x4 a = *(const u32x4*)(OL0 + ((c*16) ^ sw));
    u32x4 b = *(const u32x4*)(OL1 + ((c*16) ^ sw));
    u32x4 rr;
    #pragma unroll
    for (int k = 0; k < 4; ++k)
      rr[k] = cvtpk(b2f(a[k] & 0xffffu) + b2f(b[k] & 0xffffu),
                    b2f(a[k] >> 16)     + b2f(b[k] >> 16));
    *(u32x4*)(orow + c*8) = rr;
  }
  if (tid < 64) sbuf[h*NQ + qb + tid] = SB[tid] + SB[64 + tid];
#undef STAGE
#undef QK_NN
#undef PACK_NN
}

// ---- gather + 8-way partial reduce ----
__global__ void k_gather(const int* __restrict__ x, const float* __restrict__ langfc,
                         const int* __restrict__ inv, const float* __restrict__ sbuf,
                         const unsigned short* __restrict__ Opart, float* __restrict__ out){
  int i = blockIdx.x*256 + threadIdx.x;     // float4 index, 131072 total
  int tok = x[i >> 5];
  int d4  = i & 31;
  bool word = (tok >= 4) && (tok < VOCAB-1);
  int ci;
  if (tok < 4) ci = NQ + tok;
  else if (tok == VOCAB-1) ci = NQ + 4;
  else ci = inv[tok - 4];
  float4 v = ((const float4*)langfc)[(size_t)ci*32 + d4];
  if (word){
    float s = 0.f;
    float4 o = {0.f, 0.f, 0.f, 0.f};
    #pragma unroll
    for (int h = 0; h < NH; ++h){
      s += sbuf[h*NQ + ci];
      uint2 u = *(const uint2*)(Opart + ((size_t)h*NQ + ci)*DIM + d4*4);
      o.x += b2f(u.x & 0xffffu); o.y += b2f(u.x >> 16);
      o.z += b2f(u.y & 0xffffu); o.w += b2f(u.y >> 16);
    }
    float is = 1.f / s;
    v.x += o.x*is; v.y += o.y*is; v.z += o.z*is; v.w += o.w*is;
  }
  ((float4*)out)[i] = v;
}

extern "C" void kernel_launch(void* const* d_in, const int* in_sizes, int n_in,
                              void* d_out, int out_size, void* d_ws, size_t ws_size,
                              hipStream_t stream){
  const int*   x         = (const int*)d_in[0];
  const int*   ngram_ids = (const int*)d_in[1];
  const int*   seg       = (const int*)d_in[2];
  const float* table     = (const float*)d_in[3];
  const float* latent    = (const float*)d_in[4];
  const float* special   = (const float*)d_in[5];
  const float* maskemb   = (const float*)d_in[6];
  float* out = (float*)d_out;

  char* ws = (char*)d_ws;
  int* starts            = (int*)(ws + 0);             // 131,072
  int* flags             = (int*)(ws + 0x020000);      // 131,072
  int* inv               = (int*)(ws + 0x040000);      // 131,072
  int* list              = (int*)(ws + 0x060000);      // 16,384
  int* count             = (int*)(ws + 0x064000);      // 256
  unsigned short* langbf = (unsigned short*)(ws + 0x070000);   // 4096*128*2 = 1,048,576
  float* langfc          = (float*)(ws + 0x170000);            // 4101*128*4 ~ 2.1 MB
  unsigned short* Kbf    = (unsigned short*)(ws + 0x3A0000);   // 2,572,288
  unsigned short* VtG    = (unsigned short*)(ws + 0x620000);   // 2,572,288
  float* sbuf            = (float*)(ws + 0x8A0000);            // 8*4096*4 = 131,072
  unsigned short* Opart  = (unsigned short*)(ws + 0x8C0000);   // 8*4096*128*2 = 8,388,608
  // total ~17.6 MB

  const int SMEM = 2*64*128*2 + 2*128*64*2 + 2*64*32*2;        // 73,728 B
  (void)hipFuncSetAttribute(reinterpret_cast<const void*>(k_flash),
                            hipFuncAttributeMaxDynamicSharedMemorySize, SMEM);

  hipMemsetAsync(flags, 0, 131072, stream);
  hipMemsetAsync(count, 0, 256, stream);

  k_startsmark<<<126, 256, 0, stream>>>(seg, starts, x, flags);
  k_compact   <<<125, 256, 0, stream>>>(flags, list, inv, count);
  k_prep      <<<NT + (LPAD*DIM/8)/256, 256, 0, stream>>>(latent, Kbf, VtG);
  k_bag       <<<NQ + 5, DIM, 0, stream>>>(ngram_ids, table, starts, list, count,
                                           special, maskemb, langfc, langbf);
  k_flash     <<<512, 128, SMEM, stream>>>(langbf, Kbf, VtG, Opart, sbuf);
  k_gather    <<<512, 256, 0, stream>>>(x, langfc, inv, sbuf, Opart, out);
}

// Round 6
// 99.786 us; speedup vs baseline: 5.3394x; 1.0224x over previous
//
#include <hip/hip_runtime.h>

#define NUM_WORDS 31995
#define DIM 128
#define LATENT 10000
#define LPAD 10048
#define NT 157          // LPAD/64
#define NH 16           // l-split parts (h&7 = XCD)
#define TOTAL_NGRAMS 639900
#define VOCAB 32000
#define LOG2E 1.44269504f
#define NQ 4096         // one lang row per token position (dups recomputed)

typedef __attribute__((ext_vector_type(8))) short bf16x8;
typedef __attribute__((ext_vector_type(4))) float f32x4;
typedef __attribute__((ext_vector_type(8))) unsigned short u16x8;
typedef __attribute__((ext_vector_type(4))) short s16x4;
typedef __attribute__((ext_vector_type(2))) unsigned int u32x2;
typedef __attribute__((ext_vector_type(4))) unsigned int u32x4;

__device__ __forceinline__ unsigned short f2b(float f){
  union { float f; unsigned int u; } a; a.f = f;
  unsigned int r = (a.u + 0x7fffu + ((a.u >> 16) & 1u)) >> 16;
  return (unsigned short)r;
}
__device__ __forceinline__ float b2f(unsigned int lo16){
  union { unsigned int u; float f; } a; a.u = lo16 << 16; return a.f;
}
__device__ __forceinline__ unsigned int cvtpk(float a, float b){
  unsigned int r;
  asm("v_cvt_pk_bf16_f32 %0, %1, %2" : "=v"(r) : "v"(a), "v"(b));
  return r;
}
__device__ __forceinline__ void gload16(const void* g, void* l){
  __builtin_amdgcn_global_load_lds(
      (const __attribute__((address_space(1))) unsigned int*)g,
      (__attribute__((address_space(3))) unsigned int*)l, 16, 0, 0);
}

// ---- fused prep: segment starts (binary search) + K bf16 convert + V^T build ----
__global__ void k_prep(const int* __restrict__ seg, int* __restrict__ starts,
                       const float* __restrict__ latent,
                       unsigned short* __restrict__ Kbf, unsigned short* __restrict__ VtG){
  __shared__ unsigned short TL[128*66];
  const int tid = threadIdx.x;
  const int b = blockIdx.x;
  if (b < 126){                               // starts
    int w = b*256 + tid;
    if (w > NUM_WORDS) return;
    int lo = 0, hi = TOTAL_NGRAMS;
    while (lo < hi){ int mid = (lo + hi) >> 1; if (seg[mid] < w) lo = mid + 1; else hi = mid; }
    starts[w] = lo;
    return;
  }
  if (b < 126 + NT){                          // V^T [128][LPAD] via LDS transpose
    const int l0 = (b - 126)*64;
    #pragma unroll
    for (int it = 0; it < 32; ++it){
      int idx = it*256 + tid;
      int lr = idx >> 7, d = idx & 127;
      float xv = (l0 + lr < LATENT) ? latent[(size_t)(l0+lr)*DIM + d] : 0.f;
      TL[d*66 + lr] = f2b(xv);
    }
    __syncthreads();
    #pragma unroll
    for (int it = 0; it < 8; ++it){
      int idx4 = it*256 + tid;
      int d = idx4 >> 4, j = idx4 & 15;
      s16x4 v = (s16x4){ (short)TL[d*66 + j*4], (short)TL[d*66 + j*4 + 1],
                         (short)TL[d*66 + j*4 + 2], (short)TL[d*66 + j*4 + 3] };
      *(s16x4*)(VtG + (size_t)d*LPAD + l0 + j*4) = v;
    }
    return;
  }
  // K bf16 row-major [LPAD][128]
  int i = (b - 126 - NT)*256 + tid;
  int base = i*8;
  u16x8 v;
  if (base < LATENT*DIM){
    float4 a = *(const float4*)(latent + base);
    float4 c = *(const float4*)(latent + base + 4);
    v = (u16x8){f2b(a.x),f2b(a.y),f2b(a.z),f2b(a.w),f2b(c.x),f2b(c.y),f2b(c.z),f2b(c.w)};
  } else {
    v = (u16x8){0,0,0,0,0,0,0,0};
  }
  *(u16x8*)(Kbf + base) = v;
}

// ---- per-position bag mean-pool + tanh (specials/mask copied; Q=0 for them) ----
__global__ void k_bag(const int* __restrict__ x, const int* __restrict__ ngram_ids,
                      const float* __restrict__ table, const int* __restrict__ starts,
                      const float* __restrict__ sp, const float* __restrict__ maskemb,
                      float* __restrict__ langfc, unsigned short* __restrict__ langbf){
  int ci = blockIdx.x;            // token position 0..4095
  int d = threadIdx.x;            // 0..127
  int tok = x[ci];
  if (tok < 4){
    langfc[(size_t)ci*DIM + d] = sp[tok*DIM + d];
    langbf[ci*DIM + d] = 0;
    return;
  }
  if (tok >= VOCAB-1){
    langfc[(size_t)ci*DIM + d] = maskemb[d];
    langbf[ci*DIM + d] = 0;
    return;
  }
  int w = tok - 4;
  int s = starts[w], e = starts[w+1];
  float acc = 0.f;
  for (int t = s; t < e; ++t)
    acc += table[(size_t)ngram_ids[t]*DIM + d];
  float val = (e > s) ? tanhf(acc / (float)(e - s)) : 0.f;
  langfc[(size_t)ci*DIM + d] = val;
  langbf[ci*DIM + d] = f2b(val * LOG2E);   // Q prescaled: exp(S) = exp2(S')
}

// ---- flash attention: 2 waves x 64 shared q, phase-alternating K/V staging ----
// 40 KB LDS -> 4 blocks/CU (8 waves/CU = 2/SIMD). V(t) staged under QK(t),
// K(t+1) staged under PV(t); the existing per-phase barriers drain each stage.
__global__ __launch_bounds__(128, 2) void k_flash(
    const unsigned short* __restrict__ langbf,
    const unsigned short* __restrict__ Kbf,
    const unsigned short* __restrict__ VtG,
    unsigned short* __restrict__ Opart, float* __restrict__ sbuf)
{
  extern __shared__ unsigned short sm[];
  unsigned short* KL = sm;                   // [64][128], 16B-blk ^ (row&7)
  unsigned short* VL = sm + 8192;            // [128][64], 16B-blk ^ (d&7)
  const int tid = threadIdx.x;
  const int wv = tid >> 6;
  const int l  = tid & 63;
  const int lm = l & 15, lg = l >> 4;
  unsigned short* PB = sm + 16384 + wv*2048; // per-wave P [64 q][32 l] chunk-rotated

  const int h  = blockIdx.x & 15;            // h&7 = XCD-pinned l-part
  const int qb = (blockIdx.x >> 4) * 64;
  const int ts = (h*NT)/NH;
  const int te = ((h+1)*NT)/NH;

  // Q fragments (B-operand): col=lm, k = lg*8 + i  (all 64 q per wave)
  bf16x8 qf[4][4];
  #pragma unroll
  for (int m = 0; m < 4; ++m)
    #pragma unroll
    for (int ks = 0; ks < 4; ++ks)
      qf[m][ks] = *(const bf16x8*)(langbf + (size_t)(qb + m*16 + lm)*DIM + ks*32 + lg*8);

  int kofs[8], vofs[8];
  #pragma unroll
  for (int j = 0; j < 8; ++j){
    int c   = wv*8 + j;
    int row = c*4 + (l >> 4);
    kofs[j] = row*128 + (((l & 15) ^ (row & 7))*8);
    int d   = c*8 + (l >> 3);
    vofs[j] = d*LPAD + (((l & 7) ^ (d & 7))*8);
  }

  f32x4 oacc[4][8];
  #pragma unroll
  for (int m = 0; m < 4; ++m)
    #pragma unroll
    for (int nd = 0; nd < 8; ++nd) oacc[m][nd] = (f32x4){0.f,0.f,0.f,0.f};
  float s_r[4] = {0.f,0.f,0.f,0.f};

#define STAGE_K(T) do { \
    const unsigned short* kb_ = Kbf + (size_t)(T)*8192; \
    _Pragma("unroll") \
    for (int j = 0; j < 8; ++j) gload16(kb_ + kofs[j], KL + (wv*8+j)*512); \
  } while(0)

#define STAGE_V(T) do { \
    const unsigned short* vb_ = VtG + (size_t)(T)*64; \
    _Pragma("unroll") \
    for (int j = 0; j < 8; ++j) gload16(vb_ + vofs[j], VL + (wv*8+j)*512); \
  } while(0)

#define QK_NN(NN, SS) do { \
    const int row0 = (wv*2 + (NN))*16 + lm; \
    _Pragma("unroll") \
    for (int m = 0; m < 4; ++m) SS[m] = (f32x4){0.f,0.f,0.f,0.f}; \
    __builtin_amdgcn_s_setprio(1); \
    _Pragma("unroll") \
    for (int ks = 0; ks < 4; ++ks){ \
      bf16x8 kf = *(const bf16x8*)(KL + row0*128 + (((ks*4+lg) ^ (lm & 7))*8)); \
      _Pragma("unroll") \
      for (int m = 0; m < 4; ++m) \
        SS[m] = __builtin_amdgcn_mfma_f32_16x16x32_bf16(kf, qf[m][ks], SS[m], 0, 0, 0); \
    } \
    __builtin_amdgcn_s_setprio(0); \
  } while(0)

#define PACK_NN(NN, SS) do { \
    _Pragma("unroll") \
    for (int m = 0; m < 4; ++m){ \
      float p[4]; \
      _Pragma("unroll") \
      for (int r = 0; r < 4; ++r){ \
        float e = exp2f(SS[m][r]); \
        if (tail && (l0 + (wv*2+(NN))*16 + lg*4 + r >= LATENT)) e = 0.f; \
        p[r] = e; \
      } \
      s_r[m] += (p[0] + p[1]) + (p[2] + p[3]); \
      u32x2 pk = (u32x2){cvtpk(p[0], p[1]), cvtpk(p[2], p[3])}; \
      const int q  = m*16 + lm; \
      const int c  = (NN)*2 + (lg >> 1); \
      const int pc = (c + (lm >> 2)) & 3; \
      *(u32x2*)(PB + q*32 + pc*8 + (lg & 1)*4) = pk; \
    } \
  } while(0)

  STAGE_K(ts);
  __syncthreads();                       // K(ts) landed

  for (int t = ts; t < te; ++t){
    STAGE_V(t);                          // V(t) loads fly under QK(t)
    const int l0 = t*64;
    const bool tail = (l0 + 64 > LATENT);

    f32x4 sA[4], sB[4];
    QK_NN(0, sA);
    PACK_NN(0, sA);
    QK_NN(1, sB);                        // independent MFMAs hide P0 round-trip
    PACK_NN(1, sB);
    __syncthreads();                     // V(t) landed; all waves done with KL

    if (t + 1 < te) STAGE_K(t+1);        // K(t+1) loads fly under PV(t)

    bf16x8 pf[4];
    #pragma unroll
    for (int m = 0; m < 4; ++m){
      const int q  = m*16 + lm;
      const int pc = (lg + (lm >> 2)) & 3;
      pf[m] = *(const bf16x8*)(PB + q*32 + pc*8);
    }
    __builtin_amdgcn_s_setprio(1);
    #pragma unroll
    for (int nd = 0; nd < 8; ++nd){
      const int d = nd*16 + lm;
      bf16x8 vt = *(const bf16x8*)(VL + d*64 + (((wv*4 + lg) ^ (d & 7))*8));
      #pragma unroll
      for (int m = 0; m < 4; ++m)
        oacc[m][nd] = __builtin_amdgcn_mfma_f32_16x16x32_bf16(vt, pf[m], oacc[m][nd], 0, 0, 0);
    }
    __builtin_amdgcn_s_setprio(0);
    __syncthreads();                     // K(t+1) landed; all waves done with VL
  }

  // ---- epilogue: cross-wave reduce via LDS, coalesced bf16 store ----
  char* OLw = (char*)sm + wv*16384;          // reuse KL+VL region
  float* SB = (float*)((char*)sm + 32768);   // [2][64] row sums (PB region)
  #pragma unroll
  for (int m = 0; m < 4; ++m){
    float s = s_r[m];
    s += __shfl_xor(s, 16, 64);
    s += __shfl_xor(s, 32, 64);
    const int q = m*16 + lm;
    if (lg == 0) SB[wv*64 + q] = s;
    #pragma unroll
    for (int nd = 0; nd < 8; ++nd){
      u32x2 pk = (u32x2){cvtpk(oacc[m][nd][0], oacc[m][nd][1]),
                         cvtpk(oacc[m][nd][2], oacc[m][nd][3])};
      int byte = q*256 + (nd*16 + lg*4)*2;
      byte ^= (q & 7) << 4;
      *(u32x2*)(OLw + byte) = pk;
    }
  }
  __syncthreads();
  unsigned short* orow = Opart + ((size_t)h*NQ + qb)*DIM;
  const char* OL0 = (const char*)sm;
  const char* OL1 = (const char*)sm + 16384;
  #pragma unroll
  for (int it = 0; it < 8; ++it){
    int c = it*128 + tid;                    // 16-B chunk id (1024 total)
    int sw = ((c >> 4) & 7) << 4;
    u32x4 a = *(const u32x4*)(OL0 + ((c*16) ^ sw));
    u32x4 b = *(const u32x4*)(OL1 + ((c*16) ^ sw));
    u32x4 rr;
    #pragma unroll
    for (int k = 0; k < 4; ++k)
      rr[k] = cvtpk(b2f(a[k] & 0xffffu) + b2f(b[k] & 0xffffu),
                    b2f(a[k] >> 16)     + b2f(b[k] >> 16));
    *(u32x4*)(orow + c*8) = rr;
  }
  if (tid < 64) sbuf[h*NQ + qb + tid] = SB[tid] + SB[64 + tid];
#undef STAGE_K
#undef STAGE_V
#undef QK_NN
#undef PACK_NN
}

// ---- gather: out[i] = lang[i] + (word ? sum_h Opart[h][i] / sum_h s : 0) ----
__global__ void k_gather(const int* __restrict__ x, const float* __restrict__ langfc,
                         const float* __restrict__ sbuf,
                         const unsigned short* __restrict__ Opart, float* __restrict__ out){
  int i = blockIdx.x*256 + threadIdx.x;     // float4 index, 131072 total
  int ci  = i >> 5;                         // token position
  int d4  = i & 31;
  int tok = x[ci];
  float4 v = ((const float4*)langfc)[(size_t)ci*32 + d4];
  if (tok >= 4 && tok < VOCAB-1){
    float s = 0.f;
    float4 o = {0.f, 0.f, 0.f, 0.f};
    #pragma unroll
    for (int hh = 0; hh < NH; ++hh){
      s += sbuf[hh*NQ + ci];
      uint2 u = *(const uint2*)(Opart + ((size_t)hh*NQ + ci)*DIM + d4*4);
      o.x += b2f(u.x & 0xffffu); o.y += b2f(u.x >> 16);
      o.z += b2f(u.y & 0xffffu); o.w += b2f(u.y >> 16);
    }
    float is = 1.f / s;
    v.x += o.x*is; v.y += o.y*is; v.z += o.z*is; v.w += o.w*is;
  }
  ((float4*)out)[i] = v;
}

extern "C" void kernel_launch(void* const* d_in, const int* in_sizes, int n_in,
                              void* d_out, int out_size, void* d_ws, size_t ws_size,
                              hipStream_t stream){
  const int*   x         = (const int*)d_in[0];
  const int*   ngram_ids = (const int*)d_in[1];
  const int*   seg       = (const int*)d_in[2];
  const float* table     = (const float*)d_in[3];
  const float* latent    = (const float*)d_in[4];
  const float* special   = (const float*)d_in[5];
  const float* maskemb   = (const float*)d_in[6];
  float* out = (float*)d_out;

  char* ws = (char*)d_ws;
  int* starts            = (int*)(ws + 0);                     // 131,072
  unsigned short* langbf = (unsigned short*)(ws + 0x020000);   // 4096*128*2 = 1,048,576
  float* langfc          = (float*)(ws + 0x120000);            // 4096*128*4 = 2,097,152
  unsigned short* Kbf    = (unsigned short*)(ws + 0x320000);   // 2,572,288
  unsigned short* VtG    = (unsigned short*)(ws + 0x5A0000);   // 2,572,288
  float* sbuf            = (float*)(ws + 0x820000);            // 16*4096*4 = 262,144
  unsigned short* Opart  = (unsigned short*)(ws + 0x860000);   // 16*4096*128*2 = 16,777,216
  // total ~25.6 MB

  const int SMEM = 64*128*2 + 128*64*2 + 2*64*32*2;            // 40,960 B
  (void)hipFuncSetAttribute(reinterpret_cast<const void*>(k_flash),
                            hipFuncAttributeMaxDynamicSharedMemorySize, SMEM);

  k_prep  <<<126 + NT + (LPAD*DIM/8)/256, 256, 0, stream>>>(seg, starts, latent, Kbf, VtG);
  k_bag   <<<NQ, DIM, 0, stream>>>(x, ngram_ids, table, starts, special, maskemb,
                                   langfc, langbf);
  k_flash <<<64*NH, 128, SMEM, stream>>>(langbf, Kbf, VtG, Opart, sbuf);
  k_gather<<<512, 256, 0, stream>>>(x, langfc, sbuf, Opart, out);
}